// Round 4
// baseline (17713.461 us; speedup 1.0000x reference)
//
#include <hip/hip_runtime.h>
#include <math.h>

#define TT 4096
#define HH 1500
#define NB 250     // blocks; each owns 6 hidden units
#define NT 256     // 4 waves

typedef unsigned long long u64;

#define ALD8(p)   __hip_atomic_load((p), __ATOMIC_RELAXED, __HIP_MEMORY_SCOPE_AGENT)
#define ALD4(p)   __hip_atomic_load((p), __ATOMIC_RELAXED, __HIP_MEMORY_SCOPE_AGENT)
#define AST4(p,v) __hip_atomic_store((p), (v), __ATOMIC_RELAXED, __HIP_MEMORY_SCOPE_AGENT)

__device__ __forceinline__ float fast_sigmoid(float z) {
  return 1.0f / (1.0f + __expf(-z));
}
__device__ __forceinline__ float fast_tanh(float z) {
  float az = fabsf(z);
  float e  = __expf(-2.0f * az);
  float r  = (1.0f - e) / (1.0f + e);
  return copysignf(r, z);
}

// Persistent kernel, W_hh slice in VGPRs.
// R2: RA rematerialized the weight loads (VGPR=108, LLC-BW-bound, 17.6ms).
// R3: asm-pin killed remat but RA then SPILLED to scratch (VGPR still 108,
//     17.2ms) — the backend schedules for its default ~4 waves/EU occupancy
//     target; launch_bounds only raises the allowance, not the target.
// R4: amdgpu_waves_per_eu(1,1) sets the occupancy TARGET to 1 wave/EU, so
//     RA keeps the 144 weight values live (~220 VGPRs < 512 budget).
// h(t) exchange: published fp32s carry a 4-bit step tag in low mantissa bits
// -> one 24B atomic read gives data+validity in one LLC round trip.
__global__
__attribute__((amdgpu_flat_work_group_size(NT, NT), amdgpu_waves_per_eu(1, 1)))
void lstm_fused(
    const float* __restrict__ x,    // (4096, 20)
    const float* __restrict__ Wih,  // (6000, 20)
    const float* __restrict__ Whh,  // (6000, 1500)
    const float* __restrict__ bih,  // (6000,)
    const float* __restrict__ bhh,  // (6000,)
    const float* __restrict__ W1,   // (1875, 1500)
    const float* __restrict__ b1,   // (1875,)
    const float* __restrict__ W2,   // (20, 1875)
    const float* __restrict__ b2,   // (20,)
    float* __restrict__ out,        // (20,)
    unsigned* __restrict__ ws)
{
  const int tid = threadIdx.x;
  const int bid = blockIdx.x;
  const int wv  = tid >> 6;   // wave 0..3  (= gate index i,f,g,o)
  const int ln  = tid & 63;

  unsigned* pub  = ws;          // [2][NB][8] dwords: 6 tagged h + pad (32B lines)
  unsigned* hidp = ws + 4096;   // [1875] tagged hid values

  __shared__ __align__(16) float lds_h[1536];   // h(t), zero-padded
  __shared__ __align__(16) float lds_x[20];
  __shared__ float lds_xp[24];                  // x-proj: [gate][unit]
  __shared__ float lds_gs[4][6];                // recurrent sums: [gate][unit]
  __shared__ __align__(16) float lds_hd[1875];  // block 0 only

  if (tid < 36) lds_h[1500 + tid] = 0.0f;       // zero pad once

  // ---- resident W_hh slice: wave wv = gate wv, units 0..5 of this block ----
  // scalar layout w[u][4*m+c] = W_hh[gate wv, unit u][4*(ln+64m)+c]
  float w[6][24];
  {
    const float4* wh4 = (const float4*)Whh;     // rows are 375 float4 each
    #pragma unroll
    for (int u = 0; u < 6; ++u) {
      const float4* src = wh4 + (size_t)(wv * HH + bid * 6 + u) * 375;
      #pragma unroll
      for (int m = 0; m < 6; ++m) {
        const int idx = ln + 64 * m;
        const float4 v = (idx < 375) ? src[idx] : make_float4(0.f, 0.f, 0.f, 0.f);
        w[u][4*m+0] = v.x; w[u][4*m+1] = v.y; w[u][4*m+2] = v.z; w[u][4*m+3] = v.w;
      }
    }
  }
  // Pin: opaque op kills rematerialization (spilling prevented by waves_per_eu).
  #pragma unroll
  for (int u = 0; u < 6; ++u) {
    #pragma unroll
    for (int i = 0; i < 24; ++i) {
      asm volatile("" : "+v"(w[u][i]));
    }
  }

  // ---- x-projection rows: lanes 0..5 of wave wv -> row (gate wv, unit ln) ----
  float4 wx0, wx1, wx2, wx3, wx4;
  float bias = 0.f;
  if (ln < 6) {
    const int row = wv * HH + bid * 6 + ln;
    const float4* s = (const float4*)(Wih + row * 20);
    wx0 = s[0]; wx1 = s[1]; wx2 = s[2]; wx3 = s[3]; wx4 = s[4];
    bias = bih[row] + bhh[row];
  }

  float c = 0.f;  // cell state (threads 0..5, unit = tid)

  // init publish: h(0)=0 with tag 1 (tag(h(k)) = (k+1)&15)
  if (tid < 6) AST4(pub + (0 * NB + bid) * 8 + tid, 1u);

  float xreg = 0.f;
  if (wv == 3 && ln < 20) xreg = x[ln];   // prefetch x[0]

  for (int t = 0; t < TT; ++t) {
    const int s = t & 1;
    const unsigned tag = (unsigned)((t + 1) & 15);

    if (wv == 3 && ln < 20) {
      lds_x[ln] = xreg;                       // stage x[t] (already in reg)
      if (t + 1 < TT) xreg = x[20 * (t + 1) + ln];  // prefetch x[t+1]
    }

    // ---- poll + gather h(t): lane j pulls block j's 24B tagged line ----
    if (tid < NB) {
      const u64* line = (const u64*)(pub + (s * NB + tid) * 8);
      u64 p0, p1, p2;
      for (;;) {
        p0 = ALD8(line + 0); p1 = ALD8(line + 1); p2 = ALD8(line + 2);
        unsigned m = (((unsigned)p0) & 15u) ^ tag;
        m |= (((unsigned)(p0 >> 32)) & 15u) ^ tag;
        m |= (((unsigned)p1) & 15u) ^ tag;
        m |= (((unsigned)(p1 >> 32)) & 15u) ^ tag;
        m |= (((unsigned)p2) & 15u) ^ tag;
        m |= (((unsigned)(p2 >> 32)) & 15u) ^ tag;
        if (!m) break;
        __builtin_amdgcn_s_sleep(1);
      }
      float2* dst = (float2*)(lds_h + tid * 6);
      dst[0] = make_float2(__uint_as_float((unsigned)p0), __uint_as_float((unsigned)(p0 >> 32)));
      dst[1] = make_float2(__uint_as_float((unsigned)p1), __uint_as_float((unsigned)(p1 >> 32)));
      dst[2] = make_float2(__uint_as_float((unsigned)p2), __uint_as_float((unsigned)(p2 >> 32)));
    }
    __syncthreads();   // (A) h(t) + x[t] staged

    // ---- x projection (lanes 0..5 of each wave) ----
    if (ln < 6) {
      const float4* x4 = (const float4*)lds_x;
      const float4 a = x4[0], b4 = x4[1], c4 = x4[2], d4 = x4[3], e4 = x4[4];
      float sx = bias;
      sx += wx0.x*a.x  + wx0.y*a.y  + wx0.z*a.z  + wx0.w*a.w;
      sx += wx1.x*b4.x + wx1.y*b4.y + wx1.z*b4.z + wx1.w*b4.w;
      sx += wx2.x*c4.x + wx2.y*c4.y + wx2.z*c4.z + wx2.w*c4.w;
      sx += wx3.x*d4.x + wx3.y*d4.y + wx3.z*d4.z + wx3.w*d4.w;
      sx += wx4.x*e4.x + wx4.y*e4.y + wx4.z*e4.z + wx4.w*e4.w;
      lds_xp[wv * 6 + ln] = sx;
    }

    // ---- recurrent matvec from registers ----
    float4 hr[6];
    {
      const float4* h4 = (const float4*)lds_h;
      #pragma unroll
      for (int m = 0; m < 6; ++m) hr[m] = h4[ln + 64 * m];  // conflict-free b128
    }
    float acc[6];
    #pragma unroll
    for (int u = 0; u < 6; ++u) {
      float sum = 0.f;
      #pragma unroll
      for (int m = 0; m < 6; ++m) {
        sum = fmaf(w[u][4*m+0], hr[m].x, sum);
        sum = fmaf(w[u][4*m+1], hr[m].y, sum);
        sum = fmaf(w[u][4*m+2], hr[m].z, sum);
        sum = fmaf(w[u][4*m+3], hr[m].w, sum);
      }
      acc[u] = sum;
    }
    #pragma unroll
    for (int u = 0; u < 6; ++u) {
      float v = acc[u];
      #pragma unroll
      for (int off = 32; off > 0; off >>= 1) v += __shfl_xor(v, off, 64);
      if (ln == 0) lds_gs[wv][u] = v;
    }
    __syncthreads();   // (B) sums + xp ready

    // ---- gates + state update + tagged publish (threads 0..5) ----
    if (tid < 6) {
      const int u = tid;
      const float zi = lds_gs[0][u] + lds_xp[u];
      const float zf = lds_gs[1][u] + lds_xp[6 + u];
      const float zg = lds_gs[2][u] + lds_xp[12 + u];
      const float zo = lds_gs[3][u] + lds_xp[18 + u];
      const float ig = fast_sigmoid(zi);
      const float fg = fast_sigmoid(zf);
      const float gg = fast_tanh(zg);
      const float og = fast_sigmoid(zo);
      c = fg * c + ig * gg;
      const float hn = og * fast_tanh(c);
      const unsigned bits = (__float_as_uint(hn) & ~15u) | (unsigned)((t + 2) & 15);
      AST4(pub + (((t + 1) & 1) * NB + bid) * 8 + u, bits);
    }
  }

  // ---- gather h(TT): slot 0, tag (TT+1)&15 = 1 ----
  {
    const unsigned tagf = (unsigned)((TT + 1) & 15);
    if (tid < NB) {
      const u64* line = (const u64*)(pub + (0 * NB + tid) * 8);
      u64 p0, p1, p2;
      for (;;) {
        p0 = ALD8(line + 0); p1 = ALD8(line + 1); p2 = ALD8(line + 2);
        unsigned m = (((unsigned)p0) & 15u) ^ tagf;
        m |= (((unsigned)(p0 >> 32)) & 15u) ^ tagf;
        m |= (((unsigned)p1) & 15u) ^ tagf;
        m |= (((unsigned)(p1 >> 32)) & 15u) ^ tagf;
        m |= (((unsigned)p2) & 15u) ^ tagf;
        m |= (((unsigned)(p2 >> 32)) & 15u) ^ tagf;
        if (!m) break;
        __builtin_amdgcn_s_sleep(1);
      }
      float2* dst = (float2*)(lds_h + tid * 6);
      dst[0] = make_float2(__uint_as_float((unsigned)p0), __uint_as_float((unsigned)(p0 >> 32)));
      dst[1] = make_float2(__uint_as_float((unsigned)p1), __uint_as_float((unsigned)(p1 >> 32)));
      dst[2] = make_float2(__uint_as_float((unsigned)p2), __uint_as_float((unsigned)(p2 >> 32)));
    }
  }
  __syncthreads();

  // ---- MLP layer 1: block computes rows r = bid + 250*i ----
  {
    const float4* h4 = (const float4*)lds_h;
    for (int i = wv; i < 8; i += 4) {
      const int r = bid + 250 * i;
      if (r < 1875) {
        const float4* wrow = (const float4*)(W1 + (size_t)r * HH);
        float ss = 0.f;
        #pragma unroll
        for (int m = 0; m < 6; ++m) {
          const int idx = ln + 64 * m;
          if (idx < 375) {
            const float4 a = wrow[idx], hv = h4[idx];
            ss += a.x*hv.x + a.y*hv.y + a.z*hv.z + a.w*hv.w;
          }
        }
        #pragma unroll
        for (int off = 32; off > 0; off >>= 1) ss += __shfl_xor(ss, off, 64);
        if (ln == 0) {
          const float v = ss + b1[r];
          AST4(hidp + r, (__float_as_uint(v) & ~15u) | 5u);  // tag 5 (!= poison 10)
        }
      }
    }
  }
  if (bid != 0) return;

  // ---- block 0: gather hid, MLP layer 2, write out ----
  for (int j = tid; j < 1875; j += NT) {
    unsigned bts;
    for (;;) {
      bts = ALD4(hidp + j);
      if ((bts & 15u) == 5u) break;
      __builtin_amdgcn_s_sleep(1);
    }
    lds_hd[j] = __uint_as_float(bts);
  }
  __syncthreads();

  for (int r = wv; r < 20; r += 4) {
    float ss = 0.f;
    for (int k = ln; k < 1875; k += 64)
      ss = fmaf(W2[(size_t)r * 1875 + k], lds_hd[k], ss);
    #pragma unroll
    for (int off = 32; off > 0; off >>= 1) ss += __shfl_xor(ss, off, 64);
    if (ln == 0) out[r] = ss + b2[r];
  }
}

extern "C" void kernel_launch(void* const* d_in, const int* in_sizes, int n_in,
                              void* d_out, int out_size, void* d_ws, size_t ws_size,
                              hipStream_t stream) {
  const float* x   = (const float*)d_in[0];
  const float* Wih = (const float*)d_in[1];
  const float* Whh = (const float*)d_in[2];
  const float* bih = (const float*)d_in[3];
  const float* bhh = (const float*)d_in[4];
  const float* W1  = (const float*)d_in[5];
  const float* b1  = (const float*)d_in[6];
  const float* W2  = (const float*)d_in[7];
  const float* b2  = (const float*)d_in[8];
  float* out   = (float*)d_out;
  unsigned* ws = (unsigned*)d_ws;   // uses ~24 KB

  // 250 blocks x 256 threads at 1 block/CU (250 <= 256 CUs): all blocks
  // co-resident -> the tagged-line exchange cannot deadlock.
  hipLaunchKernelGGL(lstm_fused, dim3(NB), dim3(NT), 0, stream,
                     x, Wih, Whh, bih, bhh, W1, b1, W2, b2, out, ws);
}

// Round 5
// 13219.902 us; speedup vs baseline: 1.3399x; 1.3399x over previous
//
#include <hip/hip_runtime.h>
#include <math.h>

#define TT 4096
#define HH 1500
#define NB 250     // blocks; each owns 6 hidden units
#define NT 512     // 8 waves: wave = (gate g = wv>>1, unit-triple uo = (wv&1)*3)

typedef unsigned long long u64;

#define ALD8(p)   __hip_atomic_load((p), __ATOMIC_RELAXED, __HIP_MEMORY_SCOPE_AGENT)
#define ALD4(p)   __hip_atomic_load((p), __ATOMIC_RELAXED, __HIP_MEMORY_SCOPE_AGENT)
#define AST4(p,v) __hip_atomic_store((p), (v), __ATOMIC_RELAXED, __HIP_MEMORY_SCOPE_AGENT)

__device__ __forceinline__ float fast_sigmoid(float z) {
  return 1.0f / (1.0f + __expf(-z));
}
__device__ __forceinline__ float fast_tanh(float z) {
  float az = fabsf(z);
  float e  = __expf(-2.0f * az);
  float r  = (1.0f - e) / (1.0f + e);
  return copysignf(r, z);
}

// Persistent kernel, W_hh slice resident in LDS (144 KB of the 160 KiB/CU).
// History: R2 remat (VGPR=108, LLC-bound 17.6ms); R3 asm-pin -> RA spilled
// to scratch (17.2ms); R4 waves_per_eu(1,1) -> still spilled (VGPR=132,
// 17.7ms). VGPR-resident weights are un-achievable at HIP level; LDS is
// deterministic: ds_read_b128 streams at 85-128 B/cy/CU -> ~1.5-2.3k cy/step.
// h(t) exchange: published fp32s carry a 4-bit step tag in low mantissa bits
// -> one 24B atomic read gives data+validity in one LLC round trip.
__global__ __launch_bounds__(NT, 1) void lstm_fused(
    const float* __restrict__ x,    // (4096, 20)
    const float* __restrict__ Wih,  // (6000, 20)
    const float* __restrict__ Whh,  // (6000, 1500)
    const float* __restrict__ bih,  // (6000,)
    const float* __restrict__ bhh,  // (6000,)
    const float* __restrict__ W1,   // (1875, 1500)
    const float* __restrict__ b1,   // (1875,)
    const float* __restrict__ W2,   // (20, 1875)
    const float* __restrict__ b2,   // (20,)
    float* __restrict__ out,        // (20,)
    unsigned* __restrict__ ws)
{
  const int tid = threadIdx.x;
  const int bid = blockIdx.x;
  const int wv  = tid >> 6;   // wave 0..7
  const int ln  = tid & 63;

  unsigned* pub  = ws;          // [2][NB][8] dwords: 6 tagged h + pad (32B lines)
  unsigned* hidp = ws + 4096;   // [1875] tagged hid values

  // 24 rows x 384 float4 (375 data + 9 zero pad) = 147,456 B
  __shared__ __align__(16) float lds_w[24 * 1536];
  __shared__ __align__(16) float lds_h[1536];   // h(t), zero-padded
  __shared__ __align__(16) float lds_x[20];
  __shared__ float lds_xp[24];                  // x-proj: [gate][unit]
  __shared__ float lds_gs[4][6];                // recurrent sums: [gate][unit]
  float* lds_hd = lds_w;                        // alias (block 0, post-loop only)

  if (tid < 36) lds_h[1500 + tid] = 0.0f;       // zero pad once

  // ---- stage W_hh slice into LDS (one-time, coalesced float4 copy) ----
  {
    const float4* whh4 = (const float4*)Whh;
    float4* w4 = (float4*)lds_w;
    for (int idx = tid; idx < 24 * 384; idx += NT) {
      const int r = idx / 384, k4 = idx - r * 384;
      const int g = r / 6,  u = r - g * 6;
      const int grow = g * HH + bid * 6 + u;
      w4[idx] = (k4 < 375) ? whh4[(size_t)grow * 375 + k4]
                           : make_float4(0.f, 0.f, 0.f, 0.f);
    }
  }

  // ---- x-projection rows: waves 0..3, lanes 0..5 -> row (gate wv, unit ln) ----
  float4 wx0, wx1, wx2, wx3, wx4;
  float bias = 0.f;
  if (wv < 4 && ln < 6) {
    const int row = wv * HH + bid * 6 + ln;
    const float4* s = (const float4*)(Wih + row * 20);
    wx0 = s[0]; wx1 = s[1]; wx2 = s[2]; wx3 = s[3]; wx4 = s[4];
    bias = bih[row] + bhh[row];
  }

  float c = 0.f;  // cell state (threads 0..5, unit = tid)

  // init publish: h(0)=0 with tag 1 (tag(h(k)) = (k+1)&15)
  if (tid < 6) AST4(pub + (0 * NB + bid) * 8 + tid, 1u);

  float xreg = 0.f;
  if (wv == 7 && ln < 20) xreg = x[ln];   // prefetch x[0]

  // FMA-phase row bases (wave-constant)
  const int g  = wv >> 1;
  const int uo = (wv & 1) * 3;
  const float4* wr0 = (const float4*)lds_w + (size_t)(g * 6 + uo + 0) * 384;
  const float4* wr1 = (const float4*)lds_w + (size_t)(g * 6 + uo + 1) * 384;
  const float4* wr2 = (const float4*)lds_w + (size_t)(g * 6 + uo + 2) * 384;
  const float4* h4  = (const float4*)lds_h;

  for (int t = 0; t < TT; ++t) {
    const int s = t & 1;
    const unsigned tag = (unsigned)((t + 1) & 15);

    if (wv == 7 && ln < 20) {
      lds_x[ln] = xreg;                       // stage x[t] (already in reg)
      if (t + 1 < TT) xreg = x[20 * (t + 1) + ln];  // prefetch x[t+1]
    }

    // ---- poll + gather h(t): lane j pulls block j's 24B tagged line ----
    if (tid < NB) {
      const u64* line = (const u64*)(pub + (s * NB + tid) * 8);
      u64 p0, p1, p2;
      for (;;) {
        p0 = ALD8(line + 0); p1 = ALD8(line + 1); p2 = ALD8(line + 2);
        unsigned m = (((unsigned)p0) & 15u) ^ tag;
        m |= (((unsigned)(p0 >> 32)) & 15u) ^ tag;
        m |= (((unsigned)p1) & 15u) ^ tag;
        m |= (((unsigned)(p1 >> 32)) & 15u) ^ tag;
        m |= (((unsigned)p2) & 15u) ^ tag;
        m |= (((unsigned)(p2 >> 32)) & 15u) ^ tag;
        if (!m) break;
        __builtin_amdgcn_s_sleep(1);
      }
      float2* dst = (float2*)(lds_h + tid * 6);
      dst[0] = make_float2(__uint_as_float((unsigned)p0), __uint_as_float((unsigned)(p0 >> 32)));
      dst[1] = make_float2(__uint_as_float((unsigned)p1), __uint_as_float((unsigned)(p1 >> 32)));
      dst[2] = make_float2(__uint_as_float((unsigned)p2), __uint_as_float((unsigned)(p2 >> 32)));
    }
    __syncthreads();   // (A) h(t) + x[t] staged

    // ---- x projection (waves 0..3, lanes 0..5) ----
    if (wv < 4 && ln < 6) {
      const float4* x4 = (const float4*)lds_x;
      const float4 a = x4[0], b4 = x4[1], c4 = x4[2], d4 = x4[3], e4 = x4[4];
      float sx = bias;
      sx += wx0.x*a.x  + wx0.y*a.y  + wx0.z*a.z  + wx0.w*a.w;
      sx += wx1.x*b4.x + wx1.y*b4.y + wx1.z*b4.z + wx1.w*b4.w;
      sx += wx2.x*c4.x + wx2.y*c4.y + wx2.z*c4.z + wx2.w*c4.w;
      sx += wx3.x*d4.x + wx3.y*d4.y + wx3.z*d4.z + wx3.w*d4.w;
      sx += wx4.x*e4.x + wx4.y*e4.y + wx4.z*e4.z + wx4.w*e4.w;
      lds_xp[wv * 6 + ln] = sx;
    }

    // ---- recurrent matvec: 3 rows/wave streamed from LDS ----
    float a0 = 0.f, a1 = 0.f, a2 = 0.f;
    #pragma unroll
    for (int m = 0; m < 6; ++m) {
      const int idx = ln + 64 * m;          // < 384 (pad covers 375..383)
      const float4 hv = h4[idx];
      const float4 q0 = wr0[idx];
      const float4 q1 = wr1[idx];
      const float4 q2 = wr2[idx];
      a0 = fmaf(q0.x, hv.x, a0); a0 = fmaf(q0.y, hv.y, a0);
      a0 = fmaf(q0.z, hv.z, a0); a0 = fmaf(q0.w, hv.w, a0);
      a1 = fmaf(q1.x, hv.x, a1); a1 = fmaf(q1.y, hv.y, a1);
      a1 = fmaf(q1.z, hv.z, a1); a1 = fmaf(q1.w, hv.w, a1);
      a2 = fmaf(q2.x, hv.x, a2); a2 = fmaf(q2.y, hv.y, a2);
      a2 = fmaf(q2.z, hv.z, a2); a2 = fmaf(q2.w, hv.w, a2);
    }
    #pragma unroll
    for (int off = 32; off > 0; off >>= 1) {
      a0 += __shfl_xor(a0, off, 64);
      a1 += __shfl_xor(a1, off, 64);
      a2 += __shfl_xor(a2, off, 64);
    }
    if (ln == 0) {
      lds_gs[g][uo + 0] = a0;
      lds_gs[g][uo + 1] = a1;
      lds_gs[g][uo + 2] = a2;
    }
    __syncthreads();   // (B) sums + xp ready

    // ---- gates + state update + tagged publish (threads 0..5) ----
    if (tid < 6) {
      const int u = tid;
      const float zi = lds_gs[0][u] + lds_xp[u];
      const float zf = lds_gs[1][u] + lds_xp[6 + u];
      const float zg = lds_gs[2][u] + lds_xp[12 + u];
      const float zo = lds_gs[3][u] + lds_xp[18 + u];
      const float ig = fast_sigmoid(zi);
      const float fg = fast_sigmoid(zf);
      const float gg = fast_tanh(zg);
      const float og = fast_sigmoid(zo);
      c = fg * c + ig * gg;
      const float hn = og * fast_tanh(c);
      const unsigned bits = (__float_as_uint(hn) & ~15u) | (unsigned)((t + 2) & 15);
      AST4(pub + (((t + 1) & 1) * NB + bid) * 8 + u, bits);
    }
  }

  // ---- gather h(TT): slot 0, tag (TT+1)&15 = 1 ----
  {
    const unsigned tagf = (unsigned)((TT + 1) & 15);
    if (tid < NB) {
      const u64* line = (const u64*)(pub + (0 * NB + tid) * 8);
      u64 p0, p1, p2;
      for (;;) {
        p0 = ALD8(line + 0); p1 = ALD8(line + 1); p2 = ALD8(line + 2);
        unsigned m = (((unsigned)p0) & 15u) ^ tagf;
        m |= (((unsigned)(p0 >> 32)) & 15u) ^ tagf;
        m |= (((unsigned)p1) & 15u) ^ tagf;
        m |= (((unsigned)(p1 >> 32)) & 15u) ^ tagf;
        m |= (((unsigned)p2) & 15u) ^ tagf;
        m |= (((unsigned)(p2 >> 32)) & 15u) ^ tagf;
        if (!m) break;
        __builtin_amdgcn_s_sleep(1);
      }
      float2* dst = (float2*)(lds_h + tid * 6);
      dst[0] = make_float2(__uint_as_float((unsigned)p0), __uint_as_float((unsigned)(p0 >> 32)));
      dst[1] = make_float2(__uint_as_float((unsigned)p1), __uint_as_float((unsigned)(p1 >> 32)));
      dst[2] = make_float2(__uint_as_float((unsigned)p2), __uint_as_float((unsigned)(p2 >> 32)));
    }
  }
  __syncthreads();

  // ---- MLP layer 1: wave wv computes row r = bid + 250*wv ----
  {
    const int r = bid + 250 * wv;
    if (r < 1875) {
      const float4* wrow = (const float4*)(W1 + (size_t)r * HH);
      float ss = 0.f;
      #pragma unroll
      for (int m = 0; m < 6; ++m) {
        const int idx = ln + 64 * m;
        if (idx < 375) {
          const float4 a = wrow[idx], hv = h4[idx];
          ss += a.x*hv.x + a.y*hv.y + a.z*hv.z + a.w*hv.w;
        }
      }
      #pragma unroll
      for (int off = 32; off > 0; off >>= 1) ss += __shfl_xor(ss, off, 64);
      if (ln == 0) {
        const float v = ss + b1[r];
        AST4(hidp + r, (__float_as_uint(v) & ~15u) | 5u);  // tag 5 (!= poison 10)
      }
    }
  }
  if (bid != 0) return;

  // ---- block 0: gather hid (into lds_w alias — weights dead), MLP2, out ----
  __syncthreads();
  for (int j = tid; j < 1875; j += NT) {
    unsigned bts;
    for (;;) {
      bts = ALD4(hidp + j);
      if ((bts & 15u) == 5u) break;
      __builtin_amdgcn_s_sleep(1);
    }
    lds_hd[j] = __uint_as_float(bts);
  }
  __syncthreads();

  for (int r = wv; r < 20; r += 8) {
    float ss = 0.f;
    for (int k = ln; k < 1875; k += 64)
      ss = fmaf(W2[(size_t)r * 1875 + k], lds_hd[k], ss);
    #pragma unroll
    for (int off = 32; off > 0; off >>= 1) ss += __shfl_xor(ss, off, 64);
    if (ln == 0) out[r] = ss + b2[r];
  }
}

extern "C" void kernel_launch(void* const* d_in, const int* in_sizes, int n_in,
                              void* d_out, int out_size, void* d_ws, size_t ws_size,
                              hipStream_t stream) {
  const float* x   = (const float*)d_in[0];
  const float* Wih = (const float*)d_in[1];
  const float* Whh = (const float*)d_in[2];
  const float* bih = (const float*)d_in[3];
  const float* bhh = (const float*)d_in[4];
  const float* W1  = (const float*)d_in[5];
  const float* b1  = (const float*)d_in[6];
  const float* W2  = (const float*)d_in[7];
  const float* b2  = (const float*)d_in[8];
  float* out   = (float*)d_out;
  unsigned* ws = (unsigned*)d_ws;   // uses ~24 KB

  // 250 blocks x 512 threads, ~154 KB LDS -> exactly 1 block/CU, 250 <= 256
  // CUs: all blocks co-resident -> the tagged-line exchange cannot deadlock.
  hipLaunchKernelGGL(lstm_fused, dim3(NB), dim3(NT), 0, stream,
                     x, Wih, Whh, bih, bhh, W1, b1, W2, b2, out, ws);
}